// Round 7
// baseline (71.293 us; speedup 1.0000x reference)
//
#include <hip/hip_runtime.h>
#include <stdint.h>

#pragma clang fp contract(off)

#define NB 128
#define NC 12
#define NTT 5000
#define BLK 320

typedef unsigned int u32;

// Canonical Threefry-2x32, 20 rounds (matches JAX / Random123).
__device__ __forceinline__ void tf2(u32 k0, u32 k1, u32 c0, u32 c1, u32& o0, u32& o1) {
  u32 k2 = k0 ^ k1 ^ 0x1BD11BDAu;
  u32 x0 = c0 + k0, x1 = c1 + k1;
#define TFR(r) x0 += x1; x1 = (x1 << (r)) | (x1 >> (32 - (r))); x1 ^= x0;
  TFR(13) TFR(15) TFR(26) TFR(6)
  x0 += k1; x1 += k2 + 1u;
  TFR(17) TFR(29) TFR(16) TFR(24)
  x0 += k2; x1 += k0 + 2u;
  TFR(13) TFR(15) TFR(26) TFR(6)
  x0 += k0; x1 += k1 + 3u;
  TFR(17) TFR(29) TFR(16) TFR(24)
  x0 += k1; x1 += k2 + 4u;
  TFR(13) TFR(15) TFR(26) TFR(6)
  x0 += k2; x1 += k0 + 5u;
#undef TFR
  o0 = x0; o1 = x1;
}

// JAX f32 uniform bit->float: [1,2) - 1. Partitionable 32-bit bits = o0^o1.
__device__ __forceinline__ float u01(u32 bits) {
  return __uint_as_float((bits >> 9) | 0x3F800000u) - 1.0f;
}

// Giles erfinv core on log2 (v_log_f32 raw). Returns p; caller multiplies by x.
// w = -ln2 * l; branch w<5  <=>  l > -5/ln2. Continuous path (validated slack).
__device__ __forceinline__ float erfinv_poly(float xx) {
  float l = __builtin_amdgcn_logf(1.0f - xx);   // log2(1 - x^2)
  float p;
  if (l > -7.2134752f) {                        // w < 5
    float w = fmaf(l, -0.69314718f, -2.5f);     // (-ln2*l) - 2.5, one rounding
    p = fmaf(2.81022636e-08f, w, 3.43273939e-07f);
    p = fmaf(p, w, -3.5233877e-06f);
    p = fmaf(p, w, -4.39150654e-06f);
    p = fmaf(p, w, 0.00021858087f);
    p = fmaf(p, w, -0.00125372503f);
    p = fmaf(p, w, -0.00417768164f);
    p = fmaf(p, w, 0.246640727f);
    p = fmaf(p, w, 1.50140941f);
  } else {
    float w = l * -0.69314718f;
    w = __fsqrt_rn(w) - 3.0f;
    p = fmaf(-0.000200214257f, w, 0.000100950558f);
    p = fmaf(p, w, 0.00134934322f);
    p = fmaf(p, w, -0.00367342844f);
    p = fmaf(p, w, 0.00573950773f);
    p = fmaf(p, w, -0.0076224613f);
    p = fmaf(p, w, 0.00943887047f);
    p = fmaf(p, w, 1.00167406f);
    p = fmaf(p, w, 2.83297682f);
  }
  return p;
}

struct SSc {
  float w[7];
  float mag0, scale1, mag3, amp4, freq, ph, wf, wp;
  int start, mlen, shift;
  u32 nk0, nk1;
};

__global__ __launch_bounds__(BLK, 8) void aug_fused(
    const float* __restrict__ xin, const float* __restrict__ logits,
    const float* __restrict__ mag_neg, const float* __restrict__ mag_pos,
    const int* __restrict__ labels, float* __restrict__ xout) {
  __shared__ float rowB[NTT + 1];   // +1 pad: stage-1 reads i0+1 unclamped
  __shared__ SSc ssc[2];

  const int bc = blockIdx.x;
  const int b = bc / NC;
  const int rowbase = bc * NTT;
  const int tid = threadIdx.x;

  // ---- Parallel scalar setup on wave 0: lane L<14 owns (stage s, op j). ----
  if (tid < 64) {
    // Label dtype probe via ballot: int64 labels => all odd 32-bit words zero.
    bool nz = labels[2 * tid + 1] != 0;
    unsigned long long mk = __ballot(nz);
    const int mode64 = (mk == 0ULL) ? 1 : 0;
    const int L = tid;
    if (L < 14) {
      const int s = (L >= 7) ? 1 : 0;
      const int j = L - 7 * s;
      const int lab = mode64 ? labels[2 * b] : labels[b];
      const float lf = (float)lab;

      u32 kk0, kk1, kj0, kj1, k00, k01, o0, o1;
      tf2(0u, 42u, 0u, (u32)s, kk0, kk1);        // fold_in(key(42), s)
      tf2(kk0, kk1, 0u, (u32)j, kj0, kj1);       // own split key ks[j]
      tf2(kk0, kk1, 0u, 0u, k00, k01);           // ks[0] (gumbel key)
      tf2(k00, k01, 0u, (u32)j, o0, o1);         // gumbel bits, counter j
      float u = fmaxf(u01(o0 ^ o1), 1e-20f);
      float g = -__logf(-__logf(u));
      float v = logits[s * 7 + j] + g;

      // softmax over own group of 7 via shuffles (max exact; sum continuous)
      float vk[7];
#pragma unroll
      for (int k = 0; k < 7; ++k) vk[k] = __shfl(v, 7 * s + k);
      float m = vk[0];
#pragma unroll
      for (int k = 1; k < 7; ++k) m = fmaxf(m, vk[k]);
      float sum = 0.0f;
#pragma unroll
      for (int k = 0; k < 7; ++k) sum += __expf(vk[k] - m);
      ssc[s].w[j] = __expf(v - m) / sum;

      // magnitude |mag_neg + lf*(mag_pos - mag_neg)| (exact op order)
      float mn = mag_neg[s * 7 + j];
      float mp = mag_pos[s * 7 + j];
      float d = mp - mn;
      float pr = lf * d;
      float mgj = fabsf(mn + pr);

      if (j == 0) {
        ssc[s].mag0 = mgj;
      } else if (j == 1) {
        ssc[s].scale1 = 1.0f + mgj;
        ssc[s].nk0 = kj0; ssc[s].nk1 = kj1;      // noise key ks[1]
      } else if (j == 2) {
        int ml = (int)floorf(mgj * 5000.0f);     // exact discrete sequence
        ml = ml < 0 ? 0 : (ml > NTT ? NTT : ml);
        tf2(kj0, kj1, 0u, (u32)b, o0, o1);
        int tml = NTT - ml + 1;
        if (tml < 1) tml = 1;
        int st = (int)floorf(u01(o0 ^ o1) * (float)tml);
        ssc[s].start = st; ssc[s].mlen = ml;
      } else if (j == 3) {
        ssc[s].mag3 = mgj;
        tf2(kj0, kj1, 0u, (u32)b, o0, o1);
        float f = u01(o0 ^ o1); float fp = f * 0.3f; ssc[s].freq = fp + 0.05f;
      } else if (j == 4) {
        ssc[s].amp4 = 0.1f * mgj;
        tf2(kj0, kj1, 0u, (u32)b, o0, o1);
        ssc[s].ph = u01(o0 ^ o1) * 6.283185307179586f;
      } else if (j == 5) {
        ssc[s].shift = (int)floorf(mgj * 5000.0f);
        tf2(kj0, kj1, 0u, (u32)b, o0, o1);
        float f = u01(o0 ^ o1); float fp = f * 2.0f; ssc[s].wf = fp + 1.0f;
      } else { // j == 6
        tf2(kj0, kj1, 0u, (u32)b, o0, o1);
        ssc[s].wp = u01(o0 ^ o1) * 6.283185307179586f;
      }
    }
  }
  __syncthreads();

  const float D_T2PI = 6.283185307179586f / 4999.0f;
  const float D_BASE = 2.0f / 4999.0f;
  const float NLO = -0.9999999403953552f;  // nextafter(-1f, 0)
  const float SQRT2 = 1.4142135623730951f;

  // ---- stage 0: read x row from GLOBAL (L1-resident), write rowB (LDS) ----
  {
    const SSc sc = ssc[0];
    const float cc_m = ((sc.w[0] + sc.w[1] * sc.scale1) + sc.w[3]) + sc.w[6];
    const float cc_u = cc_m + sc.w[2];
    const float A0s = (sc.w[0] * sc.mag0) * SQRT2;
    const float A3 = sc.w[3] * sc.mag3;
    const float W4 = sc.w[4], W5 = sc.w[5];
    const float fD3 = sc.freq * D_T2PI;
    const float fD4 = sc.wf * D_T2PI;
    const u32 mstart = (u32)sc.start, mlen = (u32)sc.mlen;
    const u32 nk0 = sc.nk0, nk1 = sc.nk1;
    const float* __restrict__ rx = xin + rowbase;

    if (tid == 0) rowB[NTT] = 0.0f;   // pad for stage-1 unclamped i0+1 read

#pragma unroll 4
    for (int t = tid; t < NTT; t += BLK) {
      float tf = (float)t;
      float sin3 = __sinf(fmaf(tf, fD3, sc.ph));
      float sin4 = __sinf(fmaf(tf, fD4, sc.wp));

      float posb = fmaf(tf, D_BASE, -1.0f);
      float p = fmaf(sc.amp4, sin4, posb);
      p = fminf(1.0f, fmaxf(-1.0f, p));
      float px = fmaf(p, 2499.5f, 2499.5f);
      int i0 = (int)px;
      int i1 = min(i0 + 1, NTT - 1);   // keep clamp: global OOB on last row
      float fr = px - (float)i0;

      int rt = t - sc.shift;
      if (rt < 0) rt += NTT;

      float xv = rx[t];
      float xl = rx[i0];
      float xr = rx[i1];
      float xs = rx[rt];

      u32 o0, o1;
      tf2(nk0, nk1, 0u, (u32)(rowbase + t), o0, o1);
      float f = u01(o0 ^ o1);
      float un = fmaf(f, 2.0f, NLO);   // exact; >= NLO always
      float ei = erfinv_poly(un * un) * un;

      float cc = ((u32)(t - (int)mstart) < mlen) ? cc_m : cc_u;

      float y4 = fmaf(xr - xl, fr, xl);
      float r = xv * cc;
      r = fmaf(A0s, ei, r);
      r = fmaf(A3, sin3, r);
      r = fmaf(W4, y4, r);
      r = fmaf(W5, xs, r);

      rowB[t] = r;
    }
  }
  __syncthreads();

  // ---- stage 1: read rowB (LDS), write output row (global, coalesced) ----
  {
    const SSc sc = ssc[1];
    const float cc_m = ((sc.w[0] + sc.w[1] * sc.scale1) + sc.w[3]) + sc.w[6];
    const float cc_u = cc_m + sc.w[2];
    const float A0s = (sc.w[0] * sc.mag0) * SQRT2;
    const float A3 = sc.w[3] * sc.mag3;
    const float W4 = sc.w[4], W5 = sc.w[5];
    const float fD3 = sc.freq * D_T2PI;
    const float fD4 = sc.wf * D_T2PI;
    const u32 mstart = (u32)sc.start, mlen = (u32)sc.mlen;
    const u32 nk0 = sc.nk0, nk1 = sc.nk1;

#pragma unroll 4
    for (int t = tid; t < NTT; t += BLK) {
      float tf = (float)t;
      float sin3 = __sinf(fmaf(tf, fD3, sc.ph));
      float sin4 = __sinf(fmaf(tf, fD4, sc.wp));

      float posb = fmaf(tf, D_BASE, -1.0f);
      float p = fmaf(sc.amp4, sin4, posb);
      p = fminf(1.0f, fmaxf(-1.0f, p));
      float px = fmaf(p, 2499.5f, 2499.5f);
      int i0 = (int)px;
      float fr = px - (float)i0;

      int rt = t - sc.shift;
      if (rt < 0) rt += NTT;

      float xv = rowB[t];
      float xl = rowB[i0];         // adjacent pair: candidates for ds_read2
      float xr = rowB[i0 + 1];     // pad at rowB[5000]=0; fr==0 there => safe
      float xs = rowB[rt];

      u32 o0, o1;
      tf2(nk0, nk1, 0u, (u32)(rowbase + t), o0, o1);
      float f = u01(o0 ^ o1);
      float un = fmaf(f, 2.0f, NLO);
      float ei = erfinv_poly(un * un) * un;

      float cc = ((u32)(t - (int)mstart) < mlen) ? cc_m : cc_u;

      float y4 = fmaf(xr - xl, fr, xl);
      float r = xv * cc;
      r = fmaf(A0s, ei, r);
      r = fmaf(A3, sin3, r);
      r = fmaf(W4, y4, r);
      r = fmaf(W5, xs, r);

      xout[rowbase + t] = r;
    }
  }
}

extern "C" void kernel_launch(void* const* d_in, const int* in_sizes, int n_in,
                              void* d_out, int out_size, void* d_ws, size_t ws_size,
                              hipStream_t stream) {
  (void)in_sizes; (void)n_in; (void)d_ws; (void)ws_size; (void)out_size;
  const float* x = (const float*)d_in[0];
  const float* logits = (const float*)d_in[1];
  const float* mag_neg = (const float*)d_in[2];
  const float* mag_pos = (const float*)d_in[3];
  const int* labels = (const int*)d_in[4];
  float* out = (float*)d_out;
  hipLaunchKernelGGL(aug_fused, dim3(NB * NC), dim3(BLK), 0, stream,
                     x, logits, mag_neg, mag_pos, labels, out);
}

// Round 9
// 71.016 us; speedup vs baseline: 1.0039x; 1.0039x over previous
//
#include <hip/hip_runtime.h>
#include <stdint.h>

#pragma clang fp contract(off)

#define NBATCH 128
#define NCH 12
#define NTT 5000
#define NROWS (NBATCH * NCH)      // 1536
#define TOTAL (NROWS * NTT)       // 7,680,000
#define BLK 256
#define NBLK 2048
#define BELEM (TOTAL / NBLK)      // 3750 (spans <= 2 rows)

typedef unsigned int u32;

// Canonical Threefry-2x32, 20 rounds (matches JAX / Random123).
__device__ __forceinline__ void tf2(u32 k0, u32 k1, u32 c0, u32 c1, u32& o0, u32& o1) {
  u32 k2 = k0 ^ k1 ^ 0x1BD11BDAu;
  u32 x0 = c0 + k0, x1 = c1 + k1;
#define TFR(r) x0 += x1; x1 = (x1 << (r)) | (x1 >> (32 - (r))); x1 ^= x0;
  TFR(13) TFR(15) TFR(26) TFR(6)
  x0 += k1; x1 += k2 + 1u;
  TFR(17) TFR(29) TFR(16) TFR(24)
  x0 += k2; x1 += k0 + 2u;
  TFR(13) TFR(15) TFR(26) TFR(6)
  x0 += k0; x1 += k1 + 3u;
  TFR(17) TFR(29) TFR(16) TFR(24)
  x0 += k1; x1 += k2 + 4u;
  TFR(13) TFR(15) TFR(26) TFR(6)
  x0 += k2; x1 += k0 + 5u;
#undef TFR
  o0 = x0; o1 = x1;
}

// JAX f32 uniform bit->float: [1,2) - 1. Partitionable 32-bit bits = o0^o1.
__device__ __forceinline__ float u01(u32 bits) {
  return __uint_as_float((bits >> 9) | 0x3F800000u) - 1.0f;
}

// Giles erfinv core on log2 (raw v_log_f32). Returns p; caller multiplies by x.
// Validated rounds 6-7 (absmax unchanged vs exact path).
__device__ __forceinline__ float erfinv_poly(float xx) {
  float l = __builtin_amdgcn_logf(1.0f - xx);   // log2(1 - x^2)
  float p;
  if (l > -7.2134752f) {                        // w < 5
    float w = fmaf(l, -0.69314718f, -2.5f);
    p = fmaf(2.81022636e-08f, w, 3.43273939e-07f);
    p = fmaf(p, w, -3.5233877e-06f);
    p = fmaf(p, w, -4.39150654e-06f);
    p = fmaf(p, w, 0.00021858087f);
    p = fmaf(p, w, -0.00125372503f);
    p = fmaf(p, w, -0.00417768164f);
    p = fmaf(p, w, 0.246640727f);
    p = fmaf(p, w, 1.50140941f);
  } else {
    float w = l * -0.69314718f;
    w = __fsqrt_rn(w) - 3.0f;
    p = fmaf(-0.000200214257f, w, 0.000100950558f);
    p = fmaf(p, w, 0.00134934322f);
    p = fmaf(p, w, -0.00367342844f);
    p = fmaf(p, w, 0.00573950773f);
    p = fmaf(p, w, -0.0076224613f);
    p = fmaf(p, w, 0.00943887047f);
    p = fmaf(p, w, 1.00167406f);
    p = fmaf(p, w, 2.83297682f);
  }
  return p;
}

struct SSc {
  float w[7];
  float mag0, scale1, mag3, amp4, freq, ph, wf, wp;
  int start, mlen, shift;
  u32 nk0, nk1;
};

// Per-(stage,batch) scalar derivation for one lane owning op j.
// b = BATCH index (0..127) -- used for labels AND the per-sample RNG counter.
// All RNG / discrete sequences bit-identical to validated rounds 3-7.
__device__ __forceinline__ void derive_op(SSc* dst, int stage, int j, int b,
    int mode64, const float* __restrict__ logits,
    const float* __restrict__ mag_neg, const float* __restrict__ mag_pos,
    const int* __restrict__ labels, int lanebase) {
  const int lab = mode64 ? labels[2 * b] : labels[b];
  const float lf = (float)lab;

  u32 kk0, kk1, kj0, kj1, k00, k01, o0, o1;
  tf2(0u, 42u, 0u, (u32)stage, kk0, kk1);    // fold_in(key(42), stage)
  tf2(kk0, kk1, 0u, (u32)j, kj0, kj1);       // own split key ks[j]
  tf2(kk0, kk1, 0u, 0u, k00, k01);           // ks[0] (gumbel key)
  tf2(k00, k01, 0u, (u32)j, o0, o1);         // gumbel bits, counter j
  float u = fmaxf(u01(o0 ^ o1), 1e-20f);
  float g = -__logf(-__logf(u));
  float v = logits[stage * 7 + j] + g;

  // softmax over own group of 7 via shuffles (max exact; sum continuous)
  float vk[7];
#pragma unroll
  for (int k = 0; k < 7; ++k) vk[k] = __shfl(v, lanebase + k);
  float m = vk[0];
#pragma unroll
  for (int k = 1; k < 7; ++k) m = fmaxf(m, vk[k]);
  float sum = 0.0f;
#pragma unroll
  for (int k = 0; k < 7; ++k) sum += __expf(vk[k] - m);
  dst->w[j] = __expf(v - m) / sum;

  // magnitude |mag_neg + lf*(mag_pos - mag_neg)| (exact op order)
  float mn = mag_neg[stage * 7 + j];
  float mp = mag_pos[stage * 7 + j];
  float d = mp - mn;
  float pr = lf * d;
  float mgj = fabsf(mn + pr);

  if (j == 0) {
    dst->mag0 = mgj;
  } else if (j == 1) {
    dst->scale1 = 1.0f + mgj;
    dst->nk0 = kj0; dst->nk1 = kj1;          // noise key ks[1]
  } else if (j == 2) {
    int ml = (int)floorf(mgj * 5000.0f);     // exact discrete sequence
    ml = ml < 0 ? 0 : (ml > NTT ? NTT : ml);
    tf2(kj0, kj1, 0u, (u32)b, o0, o1);
    int tml = NTT - ml + 1;
    if (tml < 1) tml = 1;
    int st = (int)floorf(u01(o0 ^ o1) * (float)tml);
    dst->start = st; dst->mlen = ml;
  } else if (j == 3) {
    dst->mag3 = mgj;
    tf2(kj0, kj1, 0u, (u32)b, o0, o1);
    float f = u01(o0 ^ o1); float fp = f * 0.3f; dst->freq = fp + 0.05f;
  } else if (j == 4) {
    dst->amp4 = 0.1f * mgj;
    tf2(kj0, kj1, 0u, (u32)b, o0, o1);
    dst->ph = u01(o0 ^ o1) * 6.283185307179586f;
  } else if (j == 5) {
    dst->shift = (int)floorf(mgj * 5000.0f);
    tf2(kj0, kj1, 0u, (u32)b, o0, o1);
    float f = u01(o0 ^ o1); float fp = f * 2.0f; dst->wf = fp + 1.0f;
  } else { // j == 6
    tf2(kj0, kj1, 0u, (u32)b, o0, o1);
    dst->wp = u01(o0 ^ o1) * 6.283185307179586f;
  }
}

// One row-uniform segment: row-local t in [ts, te); sr/dr point at row base.
// Per-element body = validated round-6 sequence.
template <int STRIDE>
__device__ __forceinline__ void run_seg(const SSc& sc, int ts, int te, int rowbase,
    const float* __restrict__ sr, float* __restrict__ dr, int tid) {
  const float NLO = -0.9999999403953552f;  // nextafter(-1f, 0)
  const float SQRT2 = 1.4142135623730951f;
  const float D_T2PI = 6.283185307179586f / 4999.0f;
  const float D_BASE = 2.0f / 4999.0f;

  const float cc_m = ((sc.w[0] + sc.w[1] * sc.scale1) + sc.w[3]) + sc.w[6];
  const float cc_u = cc_m + sc.w[2];
  const float A0s = (sc.w[0] * sc.mag0) * SQRT2;
  const float A3 = sc.w[3] * sc.mag3;
  const float W4 = sc.w[4], W5 = sc.w[5];
  const float fD3 = sc.freq * D_T2PI;
  const float fD4 = sc.wf * D_T2PI;
  const u32 mstart = (u32)sc.start, mlen = (u32)sc.mlen;
  const u32 nk0 = sc.nk0, nk1 = sc.nk1;

#pragma unroll 4
  for (int t = ts + tid; t < te; t += STRIDE) {
    float tf = (float)t;
    float sin3 = __sinf(fmaf(tf, fD3, sc.ph));
    float sin4 = __sinf(fmaf(tf, fD4, sc.wp));

    float posb = fmaf(tf, D_BASE, -1.0f);
    float p = fmaf(sc.amp4, sin4, posb);
    p = fminf(1.0f, fmaxf(-1.0f, p));
    float px = fmaf(p, 2499.5f, 2499.5f);
    int i0 = (int)px;
    int i1 = min(i0 + 1, NTT - 1);
    float fr = px - (float)i0;

    int rt = t - sc.shift;
    if (rt < 0) rt += NTT;

    float xv = sr[t];
    float xl = sr[i0];
    float xr = sr[i1];
    float xs = sr[rt];

    u32 o0, o1;
    tf2(nk0, nk1, 0u, (u32)(rowbase + t), o0, o1);
    float f = u01(o0 ^ o1);
    float un = fmaf(f, 2.0f, NLO);   // exact; >= NLO always
    float ei = erfinv_poly(un * un) * un;

    float cc = ((u32)(t - (int)mstart) < mlen) ? cc_m : cc_u;

    float y4 = fmaf(xr - xl, fr, xl);
    float r = xv * cc;
    r = fmaf(A0s, ei, r);
    r = fmaf(A3, sin3, r);
    r = fmaf(W4, y4, r);
    r = fmaf(W5, xs, r);

    dr[t] = r;
  }
}

// One stage over a contiguous 3750-element chunk (spans <= 2 rows).
__global__ __launch_bounds__(BLK, 8) void aug_stage(
    const float* __restrict__ src, float* __restrict__ dst,
    const float* __restrict__ logits, const float* __restrict__ mag_neg,
    const float* __restrict__ mag_pos, const int* __restrict__ labels,
    int stage) {
  __shared__ SSc ssc[2];
  const int bid = blockIdx.x;
  const int tid = threadIdx.x;
  const int e0 = bid * BELEM, e1 = e0 + BELEM;
  const int r0 = e0 / NTT;
  const int rlast = (e1 - 1) / NTT;
  const int nrows = rlast - r0 + 1;

  if (tid < 64) {
    // Label dtype probe: int64 labels => all odd 32-bit words zero.
    bool nz = labels[2 * tid + 1] != 0;
    unsigned long long mk = __ballot(nz);
    const int mode64 = (mk == 0ULL) ? 1 : 0;
    const int slot = tid >> 3;
    const int j = tid & 7;
    if (tid < 16 && j < 7 && slot < nrows) {
      const int row = slot ? rlast : r0;
      derive_op(&ssc[slot], stage, j, row / NCH, mode64,
                logits, mag_neg, mag_pos, labels, slot * 8);
    }
  }
  __syncthreads();

  const int mid = min(e1, (r0 + 1) * NTT);
  {
    const int rb = r0 * NTT;
    run_seg<BLK>(ssc[0], e0 - rb, mid - rb, rb, src + rb, dst + rb, tid);
  }
  if (nrows == 2) {
    const int rb = rlast * NTT;
    run_seg<BLK>(ssc[1], 0, e1 - rb, rb, src + rb, dst + rb, tid);
  }
}

// ---- Fallback (ws too small): round-6 validated fused single-kernel ----
__global__ __launch_bounds__(256, 6) void aug_fused(
    const float* __restrict__ xin, const float* __restrict__ logits,
    const float* __restrict__ mag_neg, const float* __restrict__ mag_pos,
    const int* __restrict__ labels, float* __restrict__ xout) {
  __shared__ float rowB[NTT + 1];
  __shared__ SSc ssc[2];

  const int bc = blockIdx.x;
  const int b = bc / NCH;          // batch index
  const int rowbase = bc * NTT;
  const int tid = threadIdx.x;

  if (tid < 64) {
    bool nz = labels[2 * tid + 1] != 0;
    unsigned long long mk = __ballot(nz);
    const int mode64 = (mk == 0ULL) ? 1 : 0;
    if (tid < 14) {
      const int s = (tid >= 7) ? 1 : 0;
      const int j = tid - 7 * s;
      derive_op(&ssc[s], s, j, b, mode64,
                logits, mag_neg, mag_pos, labels, 7 * s);
    }
  }
  if (tid == 0) rowB[NTT] = 0.0f;   // pad for stage-1 unclamped i0+1 read
  __syncthreads();

  // stage 0: global x row -> LDS rowB
  run_seg<256>(ssc[0], 0, NTT, rowbase, xin + rowbase, rowB, tid);
  __syncthreads();

  // stage 1: LDS rowB -> global out (unclamped i0+1 is safe: pad + fr==0)
  {
    const SSc sc = ssc[1];
    const float NLO = -0.9999999403953552f, SQRT2 = 1.4142135623730951f;
    const float D_T2PI = 6.283185307179586f / 4999.0f;
    const float D_BASE = 2.0f / 4999.0f;
    const float cc_m = ((sc.w[0] + sc.w[1] * sc.scale1) + sc.w[3]) + sc.w[6];
    const float cc_u = cc_m + sc.w[2];
    const float A0s = (sc.w[0] * sc.mag0) * SQRT2;
    const float A3 = sc.w[3] * sc.mag3;
    const float W4 = sc.w[4], W5 = sc.w[5];
    const float fD3 = sc.freq * D_T2PI;
    const float fD4 = sc.wf * D_T2PI;
    const u32 mstart = (u32)sc.start, mlen = (u32)sc.mlen;
#pragma unroll 4
    for (int t = tid; t < NTT; t += 256) {
      float tf = (float)t;
      float sin3 = __sinf(fmaf(tf, fD3, sc.ph));
      float sin4 = __sinf(fmaf(tf, fD4, sc.wp));
      float posb = fmaf(tf, D_BASE, -1.0f);
      float p = fmaf(sc.amp4, sin4, posb);
      p = fminf(1.0f, fmaxf(-1.0f, p));
      float px = fmaf(p, 2499.5f, 2499.5f);
      int i0 = (int)px;
      float fr = px - (float)i0;
      int rt = t - sc.shift;
      if (rt < 0) rt += NTT;
      float xv = rowB[t], xl = rowB[i0], xr = rowB[i0 + 1], xs = rowB[rt];
      u32 o0, o1; tf2(sc.nk0, sc.nk1, 0u, (u32)(rowbase + t), o0, o1);
      float f = u01(o0 ^ o1);
      float un = fmaf(f, 2.0f, NLO);
      float ei = erfinv_poly(un * un) * un;
      float cc = ((u32)(t - (int)mstart) < mlen) ? cc_m : cc_u;
      float y4 = fmaf(xr - xl, fr, xl);
      float r = xv * cc;
      r = fmaf(A0s, ei, r); r = fmaf(A3, sin3, r);
      r = fmaf(W4, y4, r); r = fmaf(W5, xs, r);
      xout[rowbase + t] = r;
    }
  }
}

extern "C" void kernel_launch(void* const* d_in, const int* in_sizes, int n_in,
                              void* d_out, int out_size, void* d_ws, size_t ws_size,
                              hipStream_t stream) {
  (void)in_sizes; (void)n_in; (void)out_size;
  const float* x = (const float*)d_in[0];
  const float* logits = (const float*)d_in[1];
  const float* mag_neg = (const float*)d_in[2];
  const float* mag_pos = (const float*)d_in[3];
  const int* labels = (const int*)d_in[4];
  float* out = (float*)d_out;

  if (ws_size >= (size_t)TOTAL * sizeof(float) && d_ws != nullptr) {
    float* y = (float*)d_ws;
    hipLaunchKernelGGL(aug_stage, dim3(NBLK), dim3(BLK), 0, stream,
                       x, y, logits, mag_neg, mag_pos, labels, 0);
    hipLaunchKernelGGL(aug_stage, dim3(NBLK), dim3(BLK), 0, stream,
                       y, out, logits, mag_neg, mag_pos, labels, 1);
  } else {
    hipLaunchKernelGGL(aug_fused, dim3(NROWS), dim3(256), 0, stream,
                       x, logits, mag_neg, mag_pos, labels, out);
  }
}

// Round 10
// 65.564 us; speedup vs baseline: 1.0874x; 1.0832x over previous
//
#include <hip/hip_runtime.h>
#include <stdint.h>

#pragma clang fp contract(off)

#define NB 128
#define NC 12
#define NTT 5000
#define BLK 256

typedef unsigned int u32;

// Canonical Threefry-2x32, 20 rounds (matches JAX / Random123).
__device__ __forceinline__ void tf2(u32 k0, u32 k1, u32 c0, u32 c1, u32& o0, u32& o1) {
  u32 k2 = k0 ^ k1 ^ 0x1BD11BDAu;
  u32 x0 = c0 + k0, x1 = c1 + k1;
#define TFR(r) x0 += x1; x1 = (x1 << (r)) | (x1 >> (32 - (r))); x1 ^= x0;
  TFR(13) TFR(15) TFR(26) TFR(6)
  x0 += k1; x1 += k2 + 1u;
  TFR(17) TFR(29) TFR(16) TFR(24)
  x0 += k2; x1 += k0 + 2u;
  TFR(13) TFR(15) TFR(26) TFR(6)
  x0 += k0; x1 += k1 + 3u;
  TFR(17) TFR(29) TFR(16) TFR(24)
  x0 += k1; x1 += k2 + 4u;
  TFR(13) TFR(15) TFR(26) TFR(6)
  x0 += k2; x1 += k0 + 5u;
#undef TFR
  o0 = x0; o1 = x1;
}

// JAX f32 uniform bit->float: [1,2) - 1. Partitionable 32-bit bits = o0^o1.
__device__ __forceinline__ float u01(u32 bits) {
  return __uint_as_float((bits >> 9) | 0x3F800000u) - 1.0f;
}

// Giles erfinv core on log2 (raw v_log_f32). Returns p; caller multiplies by x.
// Validated rounds 6-7.
__device__ __forceinline__ float erfinv_poly(float xx) {
  float l = __builtin_amdgcn_logf(1.0f - xx);   // log2(1 - x^2)
  float p;
  if (l > -7.2134752f) {                        // w < 5
    float w = fmaf(l, -0.69314718f, -2.5f);
    p = fmaf(2.81022636e-08f, w, 3.43273939e-07f);
    p = fmaf(p, w, -3.5233877e-06f);
    p = fmaf(p, w, -4.39150654e-06f);
    p = fmaf(p, w, 0.00021858087f);
    p = fmaf(p, w, -0.00125372503f);
    p = fmaf(p, w, -0.00417768164f);
    p = fmaf(p, w, 0.246640727f);
    p = fmaf(p, w, 1.50140941f);
  } else {
    float w = l * -0.69314718f;
    w = __fsqrt_rn(w) - 3.0f;
    p = fmaf(-0.000200214257f, w, 0.000100950558f);
    p = fmaf(p, w, 0.00134934322f);
    p = fmaf(p, w, -0.00367342844f);
    p = fmaf(p, w, 0.00573950773f);
    p = fmaf(p, w, -0.0076224613f);
    p = fmaf(p, w, 0.00943887047f);
    p = fmaf(p, w, 1.00167406f);
    p = fmaf(p, w, 2.83297682f);
  }
  return p;
}

struct SSc {
  float w[7];
  float mag0, scale1, mag3, amp4, freq, ph, wf, wp;
  int start, mlen, shift;
  u32 nk0, nk1;
};

__global__ __launch_bounds__(BLK, 6) void aug_fused(
    const float* __restrict__ xin, const float* __restrict__ logits,
    const float* __restrict__ mag_neg, const float* __restrict__ mag_pos,
    const int* __restrict__ labels, float* __restrict__ xout) {
  __shared__ float rowB[NTT];
  __shared__ SSc ssc[2];

  const int bc = blockIdx.x;
  const int b = bc / NC;
  const int rowbase = bc * NTT;
  const int tid = threadIdx.x;

  // ---- Parallel scalar setup on wave 0: lane L<14 owns (stage s, op j). ----
  if (tid < 64) {
    // Label dtype probe via ballot: int64 labels => all odd 32-bit words zero.
    bool nz = labels[2 * tid + 1] != 0;
    unsigned long long mk = __ballot(nz);
    const int mode64 = (mk == 0ULL) ? 1 : 0;
    const int L = tid;
    if (L < 14) {
      const int s = (L >= 7) ? 1 : 0;
      const int j = L - 7 * s;
      const int lab = mode64 ? labels[2 * b] : labels[b];
      const float lf = (float)lab;

      u32 kk0, kk1, kj0, kj1, k00, k01, o0, o1;
      tf2(0u, 42u, 0u, (u32)s, kk0, kk1);        // fold_in(key(42), s)
      tf2(kk0, kk1, 0u, (u32)j, kj0, kj1);       // own split key ks[j]
      tf2(kk0, kk1, 0u, 0u, k00, k01);           // ks[0] (gumbel key)
      tf2(k00, k01, 0u, (u32)j, o0, o1);         // gumbel bits, counter j
      float u = fmaxf(u01(o0 ^ o1), 1e-20f);
      float g = -__logf(-__logf(u));
      float v = logits[s * 7 + j] + g;

      // softmax over own group of 7 via shuffles (max exact; sum continuous)
      float vk[7];
#pragma unroll
      for (int k = 0; k < 7; ++k) vk[k] = __shfl(v, 7 * s + k);
      float m = vk[0];
#pragma unroll
      for (int k = 1; k < 7; ++k) m = fmaxf(m, vk[k]);
      float sum = 0.0f;
#pragma unroll
      for (int k = 0; k < 7; ++k) sum += __expf(vk[k] - m);
      ssc[s].w[j] = __expf(v - m) / sum;

      // magnitude |mag_neg + lf*(mag_pos - mag_neg)| (exact op order)
      float mn = mag_neg[s * 7 + j];
      float mp = mag_pos[s * 7 + j];
      float d = mp - mn;
      float pr = lf * d;
      float mgj = fabsf(mn + pr);

      if (j == 0) {
        ssc[s].mag0 = mgj;
      } else if (j == 1) {
        ssc[s].scale1 = 1.0f + mgj;
        ssc[s].nk0 = kj0; ssc[s].nk1 = kj1;      // noise key ks[1]
      } else if (j == 2) {
        int ml = (int)floorf(mgj * 5000.0f);     // exact discrete sequence
        ml = ml < 0 ? 0 : (ml > NTT ? NTT : ml);
        tf2(kj0, kj1, 0u, (u32)b, o0, o1);
        int tml = NTT - ml + 1;
        if (tml < 1) tml = 1;
        int st = (int)floorf(u01(o0 ^ o1) * (float)tml);
        ssc[s].start = st; ssc[s].mlen = ml;
      } else if (j == 3) {
        ssc[s].mag3 = mgj;
        tf2(kj0, kj1, 0u, (u32)b, o0, o1);
        float f = u01(o0 ^ o1); float fp = f * 0.3f; ssc[s].freq = fp + 0.05f;
      } else if (j == 4) {
        ssc[s].amp4 = 0.1f * mgj;
        tf2(kj0, kj1, 0u, (u32)b, o0, o1);
        ssc[s].ph = u01(o0 ^ o1) * 6.283185307179586f;
      } else if (j == 5) {
        ssc[s].shift = (int)floorf(mgj * 5000.0f);
        tf2(kj0, kj1, 0u, (u32)b, o0, o1);
        float f = u01(o0 ^ o1); float fp = f * 2.0f; ssc[s].wf = fp + 1.0f;
      } else { // j == 6
        tf2(kj0, kj1, 0u, (u32)b, o0, o1);
        ssc[s].wp = u01(o0 ^ o1) * 6.283185307179586f;
      }
    }
  }
  __syncthreads();

  const float D_BASE = 2.0f / 4999.0f;
  const float NLO = -0.9999999403953552f;  // nextafter(-1f, 0)
  const float SQRT2 = 1.4142135623730951f;
  const float INV2PI = 0.15915494309189535f;
  const float INVT = 1.0f / 4999.0f;

  // ---- stage 0: read x row from GLOBAL (L1-resident), write rowB (LDS) ----
  {
    const SSc sc = ssc[0];
    const float cc_m = ((sc.w[0] + sc.w[1] * sc.scale1) + sc.w[3]) + sc.w[6];
    const float cc_u = cc_m + sc.w[2];
    const float A0s = (sc.w[0] * sc.mag0) * SQRT2;
    const float A3 = sc.w[3] * sc.mag3;
    const float W4 = sc.w[4], W5 = sc.w[5];
    // sin in REVOLUTIONS for raw v_sin_f32 (args <= ~4.05 rev; r7-validated)
    const float fR3 = sc.freq * INVT;
    const float pR3 = sc.ph * INV2PI;
    const float fR4 = sc.wf * INVT;
    const float pR4 = sc.wp * INV2PI;
    const u32 mstart = (u32)sc.start, mlen = (u32)sc.mlen;
    const u32 nk0 = sc.nk0, nk1 = sc.nk1;
    const float* __restrict__ rx = xin + rowbase;

#pragma unroll 4
    for (int t = tid; t < NTT; t += BLK) {
      float tf = (float)t;
      float sin3 = __builtin_amdgcn_sinf(fmaf(tf, fR3, pR3));
      float sin4 = __builtin_amdgcn_sinf(fmaf(tf, fR4, pR4));

      float posb = fmaf(tf, D_BASE, -1.0f);
      float p = fmaf(sc.amp4, sin4, posb);
      p = fminf(1.0f, fmaxf(-1.0f, p));
      float px = fmaf(p, 2499.5f, 2499.5f);
      int i0 = (int)px;
      int i1 = min(i0 + 1, NTT - 1);   // keep clamp: global OOB on last row
      float fr = px - (float)i0;

      int rt = t - sc.shift;
      if (rt < 0) rt += NTT;

      float xv = rx[t];
      float xl = rx[i0];
      float xr = rx[i1];
      float xs = rx[rt];

      u32 o0, o1;
      tf2(nk0, nk1, 0u, (u32)(rowbase + t), o0, o1);
      float f = u01(o0 ^ o1);
      float un = fmaf(f, 2.0f, NLO);   // exact; >= NLO always
      float ei = erfinv_poly(un * un) * un;

      float cc = ((u32)(t - (int)mstart) < mlen) ? cc_m : cc_u;

      float y4 = fmaf(xr - xl, fr, xl);
      float r = xv * cc;
      r = fmaf(A0s, ei, r);
      r = fmaf(A3, sin3, r);
      r = fmaf(W4, y4, r);
      r = fmaf(W5, xs, r);

      rowB[t] = r;
    }
  }
  __syncthreads();

  // ---- stage 1: read rowB (LDS), write output row (global, coalesced) ----
  {
    const SSc sc = ssc[1];
    const float cc_m = ((sc.w[0] + sc.w[1] * sc.scale1) + sc.w[3]) + sc.w[6];
    const float cc_u = cc_m + sc.w[2];
    const float A0s = (sc.w[0] * sc.mag0) * SQRT2;
    const float A3 = sc.w[3] * sc.mag3;
    const float W4 = sc.w[4], W5 = sc.w[5];
    const float fR3 = sc.freq * INVT;
    const float pR3 = sc.ph * INV2PI;
    const float fR4 = sc.wf * INVT;
    const float pR4 = sc.wp * INV2PI;
    const u32 mstart = (u32)sc.start, mlen = (u32)sc.mlen;
    const u32 nk0 = sc.nk0, nk1 = sc.nk1;

#pragma unroll 4
    for (int t = tid; t < NTT; t += BLK) {
      float tf = (float)t;
      float sin3 = __builtin_amdgcn_sinf(fmaf(tf, fR3, pR3));
      float sin4 = __builtin_amdgcn_sinf(fmaf(tf, fR4, pR4));

      float posb = fmaf(tf, D_BASE, -1.0f);
      float p = fmaf(sc.amp4, sin4, posb);
      p = fminf(1.0f, fmaxf(-1.0f, p));
      float px = fmaf(p, 2499.5f, 2499.5f);
      int i0 = (int)px;
      int i1 = min(i0 + 1, NTT - 1);
      float fr = px - (float)i0;

      int rt = t - sc.shift;
      if (rt < 0) rt += NTT;

      float xv = rowB[t];
      float xl = rowB[i0];
      float xr = rowB[i1];
      float xs = rowB[rt];

      u32 o0, o1;
      tf2(nk0, nk1, 0u, (u32)(rowbase + t), o0, o1);
      float f = u01(o0 ^ o1);
      float un = fmaf(f, 2.0f, NLO);
      float ei = erfinv_poly(un * un) * un;

      float cc = ((u32)(t - (int)mstart) < mlen) ? cc_m : cc_u;

      float y4 = fmaf(xr - xl, fr, xl);
      float r = xv * cc;
      r = fmaf(A0s, ei, r);
      r = fmaf(A3, sin3, r);
      r = fmaf(W4, y4, r);
      r = fmaf(W5, xs, r);

      xout[rowbase + t] = r;
    }
  }
}

extern "C" void kernel_launch(void* const* d_in, const int* in_sizes, int n_in,
                              void* d_out, int out_size, void* d_ws, size_t ws_size,
                              hipStream_t stream) {
  (void)in_sizes; (void)n_in; (void)d_ws; (void)ws_size; (void)out_size;
  const float* x = (const float*)d_in[0];
  const float* logits = (const float*)d_in[1];
  const float* mag_neg = (const float*)d_in[2];
  const float* mag_pos = (const float*)d_in[3];
  const int* labels = (const int*)d_in[4];
  float* out = (float*)d_out;
  hipLaunchKernelGGL(aug_fused, dim3(NB * NC), dim3(BLK), 0, stream,
                     x, logits, mag_neg, mag_pos, labels, out);
}